// Round 2
// baseline (131085.144 us; speedup 1.0000x reference)
//
#include <hip/hip_runtime.h>
#include <math.h>

// NCA: B=8, H=W=256, C=16, 16 steps. fp32 (bf16 MFMA rejected: ~1e3x error
// amplification over 16 steps would exceed the 7e-2 threshold).
// R1: phase-2 GEMV rebuilt: 4 lanes/pixel, perc hoisted to 128 VGPRs (32
// ds_reads instead of 2048), 4 indep z-chains, shfl_xor dx reduction (no
// dxpart LDS). LDS 71->51 KB.

#define HW 256
#define NPIX (8*HW*HW)   // 524288

__device__ __forceinline__ float4 f4max(float4 a, float4 b) {
    return make_float4(fmaxf(a.x,b.x), fmaxf(a.y,b.y), fmaxf(a.z,b.z), fmaxf(a.w,b.w));
}
__device__ __forceinline__ float4 shflx4(float4 v, int m) {
    return make_float4(__shfl_xor(v.x,m), __shfl_xor(v.y,m),
                       __shfl_xor(v.z,m), __shfl_xor(v.w,m));
}

// Precompute sobel bank (6 filters, 7x7, normalized) and W0^T (256x128).
__global__ void init_kernel(const float* __restrict__ W0,
                            float* __restrict__ W0T,
                            float* __restrict__ filt) {
    int t = blockIdx.x * blockDim.x + threadIdx.x;
    int nthreads = gridDim.x * blockDim.x;
    for (int idx = t; idx < 256*128; idx += nthreads) {
        int j = idx >> 7, k = idx & 127;
        W0T[idx] = W0[k*256 + j];
    }
    if (t < 6) {
        int f = t;
        int size = 3 + 2*(f >> 1);
        int p0 = (7 - size) >> 1;
        int isY = f & 1;
        float vals[49];
        float norm = 0.f;
        for (int a = 0; a < 7; a++) {
            for (int b = 0; b < 7; b++) {
                float v = 0.f;
                if (a >= p0 && a < p0+size && b >= p0 && b < p0+size) {
                    float fy = (float)(a - 3), fx = (float)(b - 3);
                    float den = fx*fx + fy*fy;
                    if (den == 0.f) den = 1.f;
                    v = (isY ? fy : fx) / den;
                }
                vals[a*7+b] = v;
                norm += fabsf(v);
            }
        }
        float inv = 1.f / norm;
        for (int i = 0; i < 49; i++) filt[f*49 + i] = vals[i] * inv;
    }
}

// One 8x8 pixel tile per block, 256 threads.
// Phase 1: thread=(pixel p=t&63, chan-quad q=t>>6): conv/pools -> perc in LDS.
// Phase 2: thread=(pixel p2=t>>2, sub=t&3): lane owns j = 4i|sub, full perc
//          in VGPRs, dx reduced over the 4 lanes via shfl_xor.
__launch_bounds__(256, 2)
__global__ void step_main(const float* __restrict__ x,
                          float* __restrict__ xmid,
                          float* __restrict__ alpha_out,
                          float* __restrict__ prelife_out,
                          const float* __restrict__ filt_g,
                          const float* __restrict__ W0T,
                          const float* __restrict__ b0,
                          const float* __restrict__ W1,
                          const float* __restrict__ stoch_s) {
    __shared__ float xs[14*14*20];     // 8+6 halo, 16ch padded to 20
    __shared__ float filt_s[294];
    __shared__ float perc[64*132];     // 128-ch percept per pixel, +4 pad

    const int t   = threadIdx.x;
    const int b   = blockIdx.z;
    const int ty0 = blockIdx.y * 8;
    const int tx0 = blockIdx.x * 8;

    for (int i = t; i < 294; i += 256) filt_s[i] = filt_g[i];

    // stage x tile + halo (zero pad = conv's zero padding; pools use
    // bounds-checked taps so OOB zeros are never consulted where it matters)
    for (int v = t; v < 784; v += 256) {          // 14*14*4 float4s
        int c4  = v & 3;
        int cell = v >> 2;
        int ly = cell / 14;
        int lx = cell - ly*14;
        int gy = ty0 + ly - 3, gx = tx0 + lx - 3;
        float4 val = make_float4(0.f,0.f,0.f,0.f);
        if ((unsigned)gy < 256u && (unsigned)gx < 256u)
            val = *(const float4*)&x[((((b<<8) + gy)<<8) + gx)*16 + (c4<<2)];
        *(float4*)&xs[cell*20 + (c4<<2)] = val;
    }
    __syncthreads();

    {   // ---- phase 1 ----
        const int p  = t & 63;
        const int q  = t >> 6;
        const int py = p >> 3, px = p & 7;
        const int gy = ty0 + py, gx = tx0 + px;
        const int q4 = q << 2;

        float4 y4[6];
        #pragma unroll
        for (int f = 0; f < 6; f++) y4[f] = make_float4(0.f,0.f,0.f,0.f);

        #pragma unroll
        for (int a = 0; a < 7; a++) {
            #pragma unroll
            for (int bb = 0; bb < 7; bb++) {
                float4 xv = *(const float4*)&xs[((py+a)*14 + (px+bb))*20 + q4];
                #pragma unroll
                for (int f = 0; f < 6; f++) {
                    float w = filt_s[f*49 + a*7 + bb];
                    y4[f].x = fmaf(w, xv.x, y4[f].x);
                    y4[f].y = fmaf(w, xv.y, y4[f].y);
                    y4[f].z = fmaf(w, xv.z, y4[f].z);
                    y4[f].w = fmaf(w, xv.w, y4[f].w);
                }
            }
        }
        // pool5 (values matter -> -inf pad via bounds check)
        float4 m5 = make_float4(-INFINITY,-INFINITY,-INFINITY,-INFINITY);
        #pragma unroll
        for (int dy = -2; dy <= 2; dy++) {
            #pragma unroll
            for (int dx2 = -2; dx2 <= 2; dx2++) {
                if ((unsigned)(gy+dy) < 256u && (unsigned)(gx+dx2) < 256u)
                    m5 = f4max(m5, *(const float4*)&xs[((py+3+dy)*14 + (px+3+dx2))*20 + q4]);
            }
        }
        // perc: [0:16)=x, [16+f*16+c)=y (f-major), [112:128)=pool5
        float4 xc = *(const float4*)&xs[((py+3)*14 + (px+3))*20 + q4];
        *(float4*)&perc[p*132 + q4] = xc;
        #pragma unroll
        for (int f = 0; f < 6; f++)
            *(float4*)&perc[p*132 + 16 + f*16 + q4] = y4[f];
        *(float4*)&perc[p*132 + 112 + q4] = m5;

        if (q == 0) {
            // pre-life: max3x3(alpha) > 0.1 ; zero taps can't flip this
            float pre = -INFINITY;
            #pragma unroll
            for (int dy = -1; dy <= 1; dy++) {
                #pragma unroll
                for (int dx2 = -1; dx2 <= 1; dx2++) {
                    if ((unsigned)(gy+dy) < 256u && (unsigned)(gx+dx2) < 256u)
                        pre = fmaxf(pre, xs[((py+3+dy)*14 + (px+3+dx2))*20 + 3]);
                }
            }
            prelife_out[(b << 16) + (gy << 8) + gx] = (pre > 0.1f) ? 1.f : 0.f;
        }
    }
    __syncthreads();

    // ---- phase 2: MLP ----
    const int p2  = t >> 2;
    const int sub = t & 3;

    float4 pv[32];
    #pragma unroll
    for (int k = 0; k < 32; k++)
        pv[k] = *(const float4*)&perc[p2*132 + (k << 2)];   // 4-lane broadcast

    float4 d0 = make_float4(0,0,0,0), d1 = d0, d2 = d0, d3 = d0;
    for (int i = 0; i < 64; i++) {
        const int j = (i << 2) | sub;
        const float4* wc = (const float4*)&W0T[j << 7];
        float z0 = b0[j], z1 = 0.f, z2 = 0.f, z3 = 0.f;   // 4 indep chains
        #pragma unroll
        for (int k = 0; k < 8; k++) {
            float4 wa = wc[(k<<2)+0], wb = wc[(k<<2)+1];
            float4 wcc= wc[(k<<2)+2], wd = wc[(k<<2)+3];
            float4 pa = pv[(k<<2)+0], pb = pv[(k<<2)+1];
            float4 pc = pv[(k<<2)+2], pd = pv[(k<<2)+3];
            z0 = fmaf(pa.x,wa.x, fmaf(pa.y,wa.y, fmaf(pa.z,wa.z, fmaf(pa.w,wa.w, z0))));
            z1 = fmaf(pb.x,wb.x, fmaf(pb.y,wb.y, fmaf(pb.z,wb.z, fmaf(pb.w,wb.w, z1))));
            z2 = fmaf(pc.x,wcc.x,fmaf(pc.y,wcc.y,fmaf(pc.z,wcc.z,fmaf(pc.w,wcc.w,z2))));
            z3 = fmaf(pd.x,wd.x, fmaf(pd.y,wd.y, fmaf(pd.z,wd.z, fmaf(pd.w,wd.w, z3))));
        }
        float h = fmaxf((z0 + z1) + (z2 + z3), 0.f);
        const float4* w1 = (const float4*)&W1[j << 4];
        float4 a0 = w1[0], a1 = w1[1], a2 = w1[2], a3 = w1[3];
        d0.x = fmaf(h, a0.x, d0.x); d0.y = fmaf(h, a0.y, d0.y);
        d0.z = fmaf(h, a0.z, d0.z); d0.w = fmaf(h, a0.w, d0.w);
        d1.x = fmaf(h, a1.x, d1.x); d1.y = fmaf(h, a1.y, d1.y);
        d1.z = fmaf(h, a1.z, d1.z); d1.w = fmaf(h, a1.w, d1.w);
        d2.x = fmaf(h, a2.x, d2.x); d2.y = fmaf(h, a2.y, d2.y);
        d2.z = fmaf(h, a2.z, d2.z); d2.w = fmaf(h, a2.w, d2.w);
        d3.x = fmaf(h, a3.x, d3.x); d3.y = fmaf(h, a3.y, d3.y);
        d3.z = fmaf(h, a3.z, d3.z); d3.w = fmaf(h, a3.w, d3.w);
    }
    // reduce over the 4 lanes of this pixel (lanemask 1,2 stay in-group)
    d0.x += __shfl_xor(d0.x,1); d0.y += __shfl_xor(d0.y,1);
    d0.z += __shfl_xor(d0.z,1); d0.w += __shfl_xor(d0.w,1);
    d1.x += __shfl_xor(d1.x,1); d1.y += __shfl_xor(d1.y,1);
    d1.z += __shfl_xor(d1.z,1); d1.w += __shfl_xor(d1.w,1);
    d2.x += __shfl_xor(d2.x,1); d2.y += __shfl_xor(d2.y,1);
    d2.z += __shfl_xor(d2.z,1); d2.w += __shfl_xor(d2.w,1);
    d3.x += __shfl_xor(d3.x,1); d3.y += __shfl_xor(d3.y,1);
    d3.z += __shfl_xor(d3.z,1); d3.w += __shfl_xor(d3.w,1);
    d0.x += __shfl_xor(d0.x,2); d0.y += __shfl_xor(d0.y,2);
    d0.z += __shfl_xor(d0.z,2); d0.w += __shfl_xor(d0.w,2);
    d1.x += __shfl_xor(d1.x,2); d1.y += __shfl_xor(d1.y,2);
    d1.z += __shfl_xor(d1.z,2); d1.w += __shfl_xor(d1.w,2);
    d2.x += __shfl_xor(d2.x,2); d2.y += __shfl_xor(d2.y,2);
    d2.z += __shfl_xor(d2.z,2); d2.w += __shfl_xor(d2.w,2);
    d3.x += __shfl_xor(d3.x,2); d3.y += __shfl_xor(d3.y,2);
    d3.z += __shfl_xor(d3.z,2); d3.w += __shfl_xor(d3.w,2);

    const int ppy = p2 >> 3, ppx = p2 & 7;
    const int pix2 = (b << 16) + ((ty0 + ppy) << 8) + (tx0 + ppx);
    float fire = (stoch_s[pix2] > 0.5f) ? 1.f : 0.f;
    float4 ds = (sub == 0) ? d0 : (sub == 1) ? d1 : (sub == 2) ? d2 : d3;
    float4 xc2 = pv[sub];               // perc[0:16) = x center
    float4 xn;
    xn.x = fmaf(fire, ds.x, xc2.x);
    xn.y = fmaf(fire, ds.y, xc2.y);
    xn.z = fmaf(fire, ds.z, xc2.z);
    xn.w = fmaf(fire, ds.w, xc2.w);
    *(float4*)&xmid[pix2*16 + (sub << 2)] = xn;
    if (sub == 0) alpha_out[pix2] = xn.w;   // channel 3
}

// In-place life masking: reads alpha_new from the separate plane (race-free).
__global__ void step_mask(float* __restrict__ xbuf,
                          const float* __restrict__ alpha,
                          const float* __restrict__ prelife,
                          const float* __restrict__ valid) {
    int pix = blockIdx.x * 256 + threadIdx.x;
    int b = pix >> 16;
    int y = (pix >> 8) & 255;
    int x = pix & 255;
    float m = -INFINITY;
    #pragma unroll
    for (int dy = -1; dy <= 1; dy++) {
        #pragma unroll
        for (int dxo = -1; dxo <= 1; dxo++) {
            int yy = y + dy, xx = x + dxo;
            if ((unsigned)yy < 256u && (unsigned)xx < 256u)
                m = fmaxf(m, alpha[(b << 16) + (yy << 8) + xx]);
        }
    }
    float life = (prelife[pix] != 0.f && m > 0.1f) ? 1.f : 0.f;
    float s = life * valid[pix];
    float4* xp = (float4*)&xbuf[pix << 4];
    #pragma unroll
    for (int i = 0; i < 4; i++) {
        float4 v = xp[i];
        v.x *= s; v.y *= s; v.z *= s; v.w *= s;
        xp[i] = v;
    }
}

extern "C" void kernel_launch(void* const* d_in, const int* in_sizes, int n_in,
                              void* d_out, int out_size, void* d_ws, size_t ws_size,
                              hipStream_t stream) {
    const float* x0    = (const float*)d_in[0];
    const float* valid = (const float*)d_in[1];
    const float* stoch = (const float*)d_in[2];
    const float* W0    = (const float*)d_in[3];
    const float* b0    = (const float*)d_in[4];
    const float* W1    = (const float*)d_in[5];

    float* ws      = (float*)d_ws;
    float* xA      = ws;                 // 8388608 floats
    float* alpha   = ws + 8388608;       // 524288
    float* prelife = ws + 8912896;       // 524288
    float* filt    = ws + 9437184;       // 294 (+pad)
    float* W0T     = ws + 9437568;       // 32768
    float* out     = (float*)d_out;

    init_kernel<<<64, 256, 0, stream>>>(W0, W0T, filt);

    const float* src = x0;
    for (int k = 1; k <= 16; k++) {
        float* dst = (k & 1) ? xA : out;   // step 16 (even) lands in d_out
        step_main<<<dim3(32,32,8), 256, 0, stream>>>(
            src, dst, alpha, prelife, filt, W0T, b0, W1,
            stoch + (size_t)(k-1)*NPIX);
        step_mask<<<NPIX/256, 256, 0, stream>>>(dst, alpha, prelife, valid);
        src = dst;
    }
}

// Round 3
// 129857.861 us; speedup vs baseline: 1.0095x; 1.0095x over previous
//
#include <hip/hip_runtime.h>
#include <math.h>

// NCA: B=8, H=W=256, C=16, 16 steps. fp32.
// R2 post-mortem: pv[sub] (runtime index) forced the whole pv[32] array to
// scratch (rule: runtime-indexed arrays -> local memory) -> 12x regression.
// R3 fix: epilogue x-center read from LDS perc (static layout), pv accesses
// are all compile-time-indexed -> pv lives in VGPRs.

#define HW 256
#define NPIX (8*HW*HW)   // 524288

__device__ __forceinline__ float4 f4max(float4 a, float4 b) {
    return make_float4(fmaxf(a.x,b.x), fmaxf(a.y,b.y), fmaxf(a.z,b.z), fmaxf(a.w,b.w));
}

// Precompute sobel bank (6 filters, 7x7, normalized) and W0^T (256x128).
__global__ void init_kernel(const float* __restrict__ W0,
                            float* __restrict__ W0T,
                            float* __restrict__ filt) {
    int t = blockIdx.x * blockDim.x + threadIdx.x;
    int nthreads = gridDim.x * blockDim.x;
    for (int idx = t; idx < 256*128; idx += nthreads) {
        int j = idx >> 7, k = idx & 127;
        W0T[idx] = W0[k*256 + j];
    }
    if (t < 6) {
        int f = t;
        int size = 3 + 2*(f >> 1);
        int p0 = (7 - size) >> 1;
        int isY = f & 1;
        float vals[49];
        float norm = 0.f;
        for (int a = 0; a < 7; a++) {
            for (int b = 0; b < 7; b++) {
                float v = 0.f;
                if (a >= p0 && a < p0+size && b >= p0 && b < p0+size) {
                    float fy = (float)(a - 3), fx = (float)(b - 3);
                    float den = fx*fx + fy*fy;
                    if (den == 0.f) den = 1.f;
                    v = (isY ? fy : fx) / den;
                }
                vals[a*7+b] = v;
                norm += fabsf(v);
            }
        }
        float inv = 1.f / norm;
        for (int i = 0; i < 49; i++) filt[f*49 + i] = vals[i] * inv;
    }
}

// One 8x8 pixel tile per block, 256 threads.
// Phase 1: thread=(pixel p=t&63, chan-quad q=t>>6): conv/pools -> perc in LDS.
// Phase 2: thread=(pixel p2=t>>2, sub=t&3): lane owns j = 4i|sub, full perc
//          in VGPRs (static indices ONLY), dx reduced via shfl_xor.
__launch_bounds__(256, 2)
__global__ void step_main(const float* __restrict__ x,
                          float* __restrict__ xmid,
                          float* __restrict__ alpha_out,
                          float* __restrict__ prelife_out,
                          const float* __restrict__ filt_g,
                          const float* __restrict__ W0T,
                          const float* __restrict__ b0,
                          const float* __restrict__ W1,
                          const float* __restrict__ stoch_s) {
    __shared__ float xs[14*14*20];     // 8+6 halo, 16ch padded to 20
    __shared__ float filt_s[294];
    __shared__ float perc[64*132];     // 128-ch percept per pixel, +4 pad

    const int t   = threadIdx.x;
    const int b   = blockIdx.z;
    const int ty0 = blockIdx.y * 8;
    const int tx0 = blockIdx.x * 8;

    for (int i = t; i < 294; i += 256) filt_s[i] = filt_g[i];

    // stage x tile + halo (zero pad = conv's zero padding)
    for (int v = t; v < 784; v += 256) {          // 14*14*4 float4s
        int c4  = v & 3;
        int cell = v >> 2;
        int ly = cell / 14;
        int lx = cell - ly*14;
        int gy = ty0 + ly - 3, gx = tx0 + lx - 3;
        float4 val = make_float4(0.f,0.f,0.f,0.f);
        if ((unsigned)gy < 256u && (unsigned)gx < 256u)
            val = *(const float4*)&x[((((b<<8) + gy)<<8) + gx)*16 + (c4<<2)];
        *(float4*)&xs[cell*20 + (c4<<2)] = val;
    }
    __syncthreads();

    {   // ---- phase 1 ----
        const int p  = t & 63;
        const int q  = t >> 6;
        const int py = p >> 3, px = p & 7;
        const int gy = ty0 + py, gx = tx0 + px;
        const int q4 = q << 2;

        float4 y4[6];
        #pragma unroll
        for (int f = 0; f < 6; f++) y4[f] = make_float4(0.f,0.f,0.f,0.f);

        #pragma unroll
        for (int a = 0; a < 7; a++) {
            #pragma unroll
            for (int bb = 0; bb < 7; bb++) {
                float4 xv = *(const float4*)&xs[((py+a)*14 + (px+bb))*20 + q4];
                #pragma unroll
                for (int f = 0; f < 6; f++) {
                    float w = filt_s[f*49 + a*7 + bb];
                    y4[f].x = fmaf(w, xv.x, y4[f].x);
                    y4[f].y = fmaf(w, xv.y, y4[f].y);
                    y4[f].z = fmaf(w, xv.z, y4[f].z);
                    y4[f].w = fmaf(w, xv.w, y4[f].w);
                }
            }
        }
        // pool5 (-inf pad via bounds check)
        float4 m5 = make_float4(-INFINITY,-INFINITY,-INFINITY,-INFINITY);
        #pragma unroll
        for (int dy = -2; dy <= 2; dy++) {
            #pragma unroll
            for (int dx2 = -2; dx2 <= 2; dx2++) {
                if ((unsigned)(gy+dy) < 256u && (unsigned)(gx+dx2) < 256u)
                    m5 = f4max(m5, *(const float4*)&xs[((py+3+dy)*14 + (px+3+dx2))*20 + q4]);
            }
        }
        // perc: [0:16)=x, [16+f*16+c)=y (f-major), [112:128)=pool5
        float4 xc = *(const float4*)&xs[((py+3)*14 + (px+3))*20 + q4];
        *(float4*)&perc[p*132 + q4] = xc;
        #pragma unroll
        for (int f = 0; f < 6; f++)
            *(float4*)&perc[p*132 + 16 + f*16 + q4] = y4[f];
        *(float4*)&perc[p*132 + 112 + q4] = m5;

        if (q == 0) {
            float pre = -INFINITY;
            #pragma unroll
            for (int dy = -1; dy <= 1; dy++) {
                #pragma unroll
                for (int dx2 = -1; dx2 <= 1; dx2++) {
                    if ((unsigned)(gy+dy) < 256u && (unsigned)(gx+dx2) < 256u)
                        pre = fmaxf(pre, xs[((py+3+dy)*14 + (px+3+dx2))*20 + 3]);
                }
            }
            prelife_out[(b << 16) + (gy << 8) + gx] = (pre > 0.1f) ? 1.f : 0.f;
        }
    }
    __syncthreads();

    // ---- phase 2: MLP ----
    const int p2  = t >> 2;
    const int sub = t & 3;

    float4 pv[32];
    #pragma unroll
    for (int k = 0; k < 32; k++)
        pv[k] = *(const float4*)&perc[p2*132 + (k << 2)];   // static indices only

    float4 d0 = make_float4(0,0,0,0), d1 = d0, d2 = d0, d3 = d0;
    for (int i = 0; i < 64; i++) {
        const int j = (i << 2) | sub;
        const float4* wc = (const float4*)&W0T[j << 7];
        float z0 = b0[j], z1 = 0.f, z2 = 0.f, z3 = 0.f;   // 4 indep chains
        #pragma unroll
        for (int k = 0; k < 8; k++) {
            float4 wa = wc[(k<<2)+0], wb = wc[(k<<2)+1];
            float4 wcc= wc[(k<<2)+2], wd = wc[(k<<2)+3];
            float4 pa = pv[(k<<2)+0], pb = pv[(k<<2)+1];
            float4 pc = pv[(k<<2)+2], pd = pv[(k<<2)+3];
            z0 = fmaf(pa.x,wa.x, fmaf(pa.y,wa.y, fmaf(pa.z,wa.z, fmaf(pa.w,wa.w, z0))));
            z1 = fmaf(pb.x,wb.x, fmaf(pb.y,wb.y, fmaf(pb.z,wb.z, fmaf(pb.w,wb.w, z1))));
            z2 = fmaf(pc.x,wcc.x,fmaf(pc.y,wcc.y,fmaf(pc.z,wcc.z,fmaf(pc.w,wcc.w,z2))));
            z3 = fmaf(pd.x,wd.x, fmaf(pd.y,wd.y, fmaf(pd.z,wd.z, fmaf(pd.w,wd.w, z3))));
        }
        float h = fmaxf((z0 + z1) + (z2 + z3), 0.f);
        const float4* w1 = (const float4*)&W1[j << 4];
        float4 a0 = w1[0], a1 = w1[1], a2 = w1[2], a3 = w1[3];
        d0.x = fmaf(h, a0.x, d0.x); d0.y = fmaf(h, a0.y, d0.y);
        d0.z = fmaf(h, a0.z, d0.z); d0.w = fmaf(h, a0.w, d0.w);
        d1.x = fmaf(h, a1.x, d1.x); d1.y = fmaf(h, a1.y, d1.y);
        d1.z = fmaf(h, a1.z, d1.z); d1.w = fmaf(h, a1.w, d1.w);
        d2.x = fmaf(h, a2.x, d2.x); d2.y = fmaf(h, a2.y, d2.y);
        d2.z = fmaf(h, a2.z, d2.z); d2.w = fmaf(h, a2.w, d2.w);
        d3.x = fmaf(h, a3.x, d3.x); d3.y = fmaf(h, a3.y, d3.y);
        d3.z = fmaf(h, a3.z, d3.z); d3.w = fmaf(h, a3.w, d3.w);
    }
    // reduce over the 4 lanes of this pixel
    d0.x += __shfl_xor(d0.x,1); d0.y += __shfl_xor(d0.y,1);
    d0.z += __shfl_xor(d0.z,1); d0.w += __shfl_xor(d0.w,1);
    d1.x += __shfl_xor(d1.x,1); d1.y += __shfl_xor(d1.y,1);
    d1.z += __shfl_xor(d1.z,1); d1.w += __shfl_xor(d1.w,1);
    d2.x += __shfl_xor(d2.x,1); d2.y += __shfl_xor(d2.y,1);
    d2.z += __shfl_xor(d2.z,1); d2.w += __shfl_xor(d2.w,1);
    d3.x += __shfl_xor(d3.x,1); d3.y += __shfl_xor(d3.y,1);
    d3.z += __shfl_xor(d3.z,1); d3.w += __shfl_xor(d3.w,1);
    d0.x += __shfl_xor(d0.x,2); d0.y += __shfl_xor(d0.y,2);
    d0.z += __shfl_xor(d0.z,2); d0.w += __shfl_xor(d0.w,2);
    d1.x += __shfl_xor(d1.x,2); d1.y += __shfl_xor(d1.y,2);
    d1.z += __shfl_xor(d1.z,2); d1.w += __shfl_xor(d1.w,2);
    d2.x += __shfl_xor(d2.x,2); d2.y += __shfl_xor(d2.y,2);
    d2.z += __shfl_xor(d2.z,2); d2.w += __shfl_xor(d2.w,2);
    d3.x += __shfl_xor(d3.x,2); d3.y += __shfl_xor(d3.y,2);
    d3.z += __shfl_xor(d3.z,2); d3.w += __shfl_xor(d3.w,2);

    const int ppy = p2 >> 3, ppx = p2 & 7;
    const int pix2 = (b << 16) + ((ty0 + ppy) << 8) + (tx0 + ppx);
    float fire = (stoch_s[pix2] > 0.5f) ? 1.f : 0.f;
    float4 ds = (sub == 0) ? d0 : (sub == 1) ? d1 : (sub == 2) ? d2 : d3;
    // x-center from LDS (NOT pv[sub]: runtime index would force pv to scratch)
    float4 xc2 = *(const float4*)&perc[p2*132 + (sub << 2)];
    float4 xn;
    xn.x = fmaf(fire, ds.x, xc2.x);
    xn.y = fmaf(fire, ds.y, xc2.y);
    xn.z = fmaf(fire, ds.z, xc2.z);
    xn.w = fmaf(fire, ds.w, xc2.w);
    *(float4*)&xmid[pix2*16 + (sub << 2)] = xn;
    if (sub == 0) alpha_out[pix2] = xn.w;   // channel 3
}

// In-place life masking: reads alpha_new from the separate plane (race-free).
__global__ void step_mask(float* __restrict__ xbuf,
                          const float* __restrict__ alpha,
                          const float* __restrict__ prelife,
                          const float* __restrict__ valid) {
    int pix = blockIdx.x * 256 + threadIdx.x;
    int b = pix >> 16;
    int y = (pix >> 8) & 255;
    int x = pix & 255;
    float m = -INFINITY;
    #pragma unroll
    for (int dy = -1; dy <= 1; dy++) {
        #pragma unroll
        for (int dxo = -1; dxo <= 1; dxo++) {
            int yy = y + dy, xx = x + dxo;
            if ((unsigned)yy < 256u && (unsigned)xx < 256u)
                m = fmaxf(m, alpha[(b << 16) + (yy << 8) + xx]);
        }
    }
    float life = (prelife[pix] != 0.f && m > 0.1f) ? 1.f : 0.f;
    float s = life * valid[pix];
    float4* xp = (float4*)&xbuf[pix << 4];
    #pragma unroll
    for (int i = 0; i < 4; i++) {
        float4 v = xp[i];
        v.x *= s; v.y *= s; v.z *= s; v.w *= s;
        xp[i] = v;
    }
}

extern "C" void kernel_launch(void* const* d_in, const int* in_sizes, int n_in,
                              void* d_out, int out_size, void* d_ws, size_t ws_size,
                              hipStream_t stream) {
    const float* x0    = (const float*)d_in[0];
    const float* valid = (const float*)d_in[1];
    const float* stoch = (const float*)d_in[2];
    const float* W0    = (const float*)d_in[3];
    const float* b0    = (const float*)d_in[4];
    const float* W1    = (const float*)d_in[5];

    float* ws      = (float*)d_ws;
    float* xA      = ws;                 // 8388608 floats
    float* alpha   = ws + 8388608;       // 524288
    float* prelife = ws + 8912896;       // 524288
    float* filt    = ws + 9437184;       // 294 (+pad)
    float* W0T     = ws + 9437568;       // 32768
    float* out     = (float*)d_out;

    init_kernel<<<64, 256, 0, stream>>>(W0, W0T, filt);

    const float* src = x0;
    for (int k = 1; k <= 16; k++) {
        float* dst = (k & 1) ? xA : out;   // step 16 (even) lands in d_out
        step_main<<<dim3(32,32,8), 256, 0, stream>>>(
            src, dst, alpha, prelife, filt, W0T, b0, W1,
            stoch + (size_t)(k-1)*NPIX);
        step_mask<<<NPIX/256, 256, 0, stream>>>(dst, alpha, prelife, valid);
        src = dst;
    }
}

// Round 4
// 72816.583 us; speedup vs baseline: 1.8002x; 1.7834x over previous
//
#include <hip/hip_runtime.h>
#include <math.h>

// NCA: B=8, H=W=256, C=16, 16 steps. fp32.
// R3 post-mortem: pv[32] float4 spilled to scratch even with static indices
// (VGPR budget ~128-170 from LDS-bound occupancy; 128-reg array + accs can't
// fit). RULE: no >~64-float per-thread arrays, period.
// R4: phase-2 = register-tile GEMM, 2 pix x 32 j per thread:
//   k-loop: 2 scalar LDS perc reads + 8 float4 W0 loads (native [k][j] layout,
//   L2-resident) + 64 FMA. acc[2][32]=64 regs, peak ~120. GEMM2 streams W1.
//   j-reduction via shfl_xor(1,2,4); dx parked in recycled xs LDS region.

#define HW 256
#define NPIX (8*HW*HW)   // 524288

__device__ __forceinline__ float4 f4max(float4 a, float4 b) {
    return make_float4(fmaxf(a.x,b.x), fmaxf(a.y,b.y), fmaxf(a.z,b.z), fmaxf(a.w,b.w));
}

// Precompute sobel bank (6 filters, 7x7, normalized). (W0 used directly now.)
__global__ void init_kernel(const float* __restrict__ W0,
                            float* __restrict__ filt) {
    int t = blockIdx.x * blockDim.x + threadIdx.x;
    if (t < 6) {
        int f = t;
        int size = 3 + 2*(f >> 1);
        int p0 = (7 - size) >> 1;
        int isY = f & 1;
        float vals[49];
        float norm = 0.f;
        for (int a = 0; a < 7; a++) {
            for (int b = 0; b < 7; b++) {
                float v = 0.f;
                if (a >= p0 && a < p0+size && b >= p0 && b < p0+size) {
                    float fy = (float)(a - 3), fx = (float)(b - 3);
                    float den = fx*fx + fy*fy;
                    if (den == 0.f) den = 1.f;
                    v = (isY ? fy : fx) / den;
                }
                vals[a*7+b] = v;
                norm += fabsf(v);
            }
        }
        float inv = 1.f / norm;
        for (int i = 0; i < 49; i++) filt[f*49 + i] = vals[i] * inv;
    }
}

// One 8x8 pixel tile per block, 256 threads.
// Phase 1: thread=(pixel p=t&63, chan-quad q=t>>6): conv/pools -> perc in LDS.
// Phase 2: thread=(jg=t&7, pg=t>>3): 2-pix x 32-j register tile.
__launch_bounds__(256, 2)
__global__ void step_main(const float* __restrict__ x,
                          float* __restrict__ xmid,
                          float* __restrict__ alpha_out,
                          float* __restrict__ prelife_out,
                          const float* __restrict__ filt_g,
                          const float* __restrict__ W0,
                          const float* __restrict__ b0,
                          const float* __restrict__ W1,
                          const float* __restrict__ stoch_s) {
    __shared__ float xs[14*14*20];     // phase1: halo tile; phase2 tail: dx park [64][20]
    __shared__ float filt_s[294];
    __shared__ float perc[64*132];     // 128-ch percept per pixel, +4 pad

    const int t   = threadIdx.x;
    const int b   = blockIdx.z;
    const int ty0 = blockIdx.y * 8;
    const int tx0 = blockIdx.x * 8;

    for (int i = t; i < 294; i += 256) filt_s[i] = filt_g[i];

    // stage x tile + halo (zero pad = conv's zero padding)
    for (int v = t; v < 784; v += 256) {          // 14*14*4 float4s
        int c4  = v & 3;
        int cell = v >> 2;
        int ly = cell / 14;
        int lx = cell - ly*14;
        int gy = ty0 + ly - 3, gx = tx0 + lx - 3;
        float4 val = make_float4(0.f,0.f,0.f,0.f);
        if ((unsigned)gy < 256u && (unsigned)gx < 256u)
            val = *(const float4*)&x[((((b<<8) + gy)<<8) + gx)*16 + (c4<<2)];
        *(float4*)&xs[cell*20 + (c4<<2)] = val;
    }
    __syncthreads();

    {   // ---- phase 1: conv + pools -> perc ----
        const int p  = t & 63;
        const int q  = t >> 6;
        const int py = p >> 3, px = p & 7;
        const int gy = ty0 + py, gx = tx0 + px;
        const int q4 = q << 2;

        float4 y4[6];
        #pragma unroll
        for (int f = 0; f < 6; f++) y4[f] = make_float4(0.f,0.f,0.f,0.f);

        #pragma unroll
        for (int a = 0; a < 7; a++) {
            #pragma unroll
            for (int bb = 0; bb < 7; bb++) {
                float4 xv = *(const float4*)&xs[((py+a)*14 + (px+bb))*20 + q4];
                #pragma unroll
                for (int f = 0; f < 6; f++) {
                    float w = filt_s[f*49 + a*7 + bb];
                    y4[f].x = fmaf(w, xv.x, y4[f].x);
                    y4[f].y = fmaf(w, xv.y, y4[f].y);
                    y4[f].z = fmaf(w, xv.z, y4[f].z);
                    y4[f].w = fmaf(w, xv.w, y4[f].w);
                }
            }
        }
        float4 m5 = make_float4(-INFINITY,-INFINITY,-INFINITY,-INFINITY);
        #pragma unroll
        for (int dy = -2; dy <= 2; dy++) {
            #pragma unroll
            for (int dx2 = -2; dx2 <= 2; dx2++) {
                if ((unsigned)(gy+dy) < 256u && (unsigned)(gx+dx2) < 256u)
                    m5 = f4max(m5, *(const float4*)&xs[((py+3+dy)*14 + (px+3+dx2))*20 + q4]);
            }
        }
        // perc: [0:16)=x, [16+f*16+c)=y (f-major), [112:128)=pool5
        float4 xc = *(const float4*)&xs[((py+3)*14 + (px+3))*20 + q4];
        *(float4*)&perc[p*132 + q4] = xc;
        #pragma unroll
        for (int f = 0; f < 6; f++)
            *(float4*)&perc[p*132 + 16 + f*16 + q4] = y4[f];
        *(float4*)&perc[p*132 + 112 + q4] = m5;

        if (q == 0) {
            float pre = -INFINITY;
            #pragma unroll
            for (int dy = -1; dy <= 1; dy++) {
                #pragma unroll
                for (int dx2 = -1; dx2 <= 1; dx2++) {
                    if ((unsigned)(gy+dy) < 256u && (unsigned)(gx+dx2) < 256u)
                        pre = fmaxf(pre, xs[((py+3+dy)*14 + (px+3+dx2))*20 + 3]);
                }
            }
            prelife_out[(b << 16) + (gy << 8) + gx] = (pre > 0.1f) ? 1.f : 0.f;
        }
    }
    __syncthreads();   // xs dead after this point; region reused for dx park

    // ---- phase 2: MLP, 2 pix x 32 j per thread ----
    const int jg = t & 7;          // j-range [jg*32, jg*32+32)
    const int pg = t >> 3;         // pixels {2pg, 2pg+1}
    const int p0 = pg << 1;
    const int jbase = jg << 5;

    float acc0[32], acc1[32];
    #pragma unroll
    for (int jj = 0; jj < 32; jj++) { acc0[jj] = 0.f; acc1[jj] = 0.f; }

    const float* percA = &perc[p0 * 132];
    const float* percB = &perc[(p0 + 1) * 132];

    #pragma unroll 2
    for (int k = 0; k < 128; k++) {
        float a0 = percA[k];
        float a1 = percB[k];
        const float4* wrow = (const float4*)(W0 + k*256 + jbase);
        #pragma unroll
        for (int qq = 0; qq < 8; qq++) {
            float4 wv = wrow[qq];
            acc0[qq*4+0] = fmaf(a0, wv.x, acc0[qq*4+0]);
            acc0[qq*4+1] = fmaf(a0, wv.y, acc0[qq*4+1]);
            acc0[qq*4+2] = fmaf(a0, wv.z, acc0[qq*4+2]);
            acc0[qq*4+3] = fmaf(a0, wv.w, acc0[qq*4+3]);
            acc1[qq*4+0] = fmaf(a1, wv.x, acc1[qq*4+0]);
            acc1[qq*4+1] = fmaf(a1, wv.y, acc1[qq*4+1]);
            acc1[qq*4+2] = fmaf(a1, wv.z, acc1[qq*4+2]);
            acc1[qq*4+3] = fmaf(a1, wv.w, acc1[qq*4+3]);
        }
    }

    // h = relu(acc + b0)
    {
        const float4* b0v = (const float4*)(b0 + jbase);
        #pragma unroll
        for (int qq = 0; qq < 8; qq++) {
            float4 bv = b0v[qq];
            acc0[qq*4+0] = fmaxf(acc0[qq*4+0] + bv.x, 0.f);
            acc0[qq*4+1] = fmaxf(acc0[qq*4+1] + bv.y, 0.f);
            acc0[qq*4+2] = fmaxf(acc0[qq*4+2] + bv.z, 0.f);
            acc0[qq*4+3] = fmaxf(acc0[qq*4+3] + bv.w, 0.f);
            acc1[qq*4+0] = fmaxf(acc1[qq*4+0] + bv.x, 0.f);
            acc1[qq*4+1] = fmaxf(acc1[qq*4+1] + bv.y, 0.f);
            acc1[qq*4+2] = fmaxf(acc1[qq*4+2] + bv.z, 0.f);
            acc1[qq*4+3] = fmaxf(acc1[qq*4+3] + bv.w, 0.f);
        }
    }

    // GEMM2: dx[2][16] += h * W1 rows (streamed)
    float dx0[16], dx1[16];
    #pragma unroll
    for (int c = 0; c < 16; c++) { dx0[c] = 0.f; dx1[c] = 0.f; }
    #pragma unroll 4
    for (int jj = 0; jj < 32; jj++) {
        const float4* w1r = (const float4*)(W1 + (size_t)(jbase + jj) * 16);
        float4 wa = w1r[0], wb = w1r[1], wc = w1r[2], wd = w1r[3];
        float h0 = acc0[jj], h1 = acc1[jj];
        dx0[0]  = fmaf(h0, wa.x, dx0[0]);  dx0[1]  = fmaf(h0, wa.y, dx0[1]);
        dx0[2]  = fmaf(h0, wa.z, dx0[2]);  dx0[3]  = fmaf(h0, wa.w, dx0[3]);
        dx0[4]  = fmaf(h0, wb.x, dx0[4]);  dx0[5]  = fmaf(h0, wb.y, dx0[5]);
        dx0[6]  = fmaf(h0, wb.z, dx0[6]);  dx0[7]  = fmaf(h0, wb.w, dx0[7]);
        dx0[8]  = fmaf(h0, wc.x, dx0[8]);  dx0[9]  = fmaf(h0, wc.y, dx0[9]);
        dx0[10] = fmaf(h0, wc.z, dx0[10]); dx0[11] = fmaf(h0, wc.w, dx0[11]);
        dx0[12] = fmaf(h0, wd.x, dx0[12]); dx0[13] = fmaf(h0, wd.y, dx0[13]);
        dx0[14] = fmaf(h0, wd.z, dx0[14]); dx0[15] = fmaf(h0, wd.w, dx0[15]);
        dx1[0]  = fmaf(h1, wa.x, dx1[0]);  dx1[1]  = fmaf(h1, wa.y, dx1[1]);
        dx1[2]  = fmaf(h1, wa.z, dx1[2]);  dx1[3]  = fmaf(h1, wa.w, dx1[3]);
        dx1[4]  = fmaf(h1, wb.x, dx1[4]);  dx1[5]  = fmaf(h1, wb.y, dx1[5]);
        dx1[6]  = fmaf(h1, wb.z, dx1[6]);  dx1[7]  = fmaf(h1, wb.w, dx1[7]);
        dx1[8]  = fmaf(h1, wc.x, dx1[8]);  dx1[9]  = fmaf(h1, wc.y, dx1[9]);
        dx1[10] = fmaf(h1, wc.z, dx1[10]); dx1[11] = fmaf(h1, wc.w, dx1[11]);
        dx1[12] = fmaf(h1, wd.x, dx1[12]); dx1[13] = fmaf(h1, wd.y, dx1[13]);
        dx1[14] = fmaf(h1, wd.z, dx1[14]); dx1[15] = fmaf(h1, wd.w, dx1[15]);
    }

    // reduce dx over the 8 jg lanes (masks 1,2,4 stay within a wave)
    #pragma unroll
    for (int c = 0; c < 16; c++) {
        dx0[c] += __shfl_xor(dx0[c], 1);
        dx1[c] += __shfl_xor(dx1[c], 1);
    }
    #pragma unroll
    for (int c = 0; c < 16; c++) {
        dx0[c] += __shfl_xor(dx0[c], 2);
        dx1[c] += __shfl_xor(dx1[c], 2);
    }
    #pragma unroll
    for (int c = 0; c < 16; c++) {
        dx0[c] += __shfl_xor(dx0[c], 4);
        dx1[c] += __shfl_xor(dx1[c], 4);
    }

    // park dx in recycled xs region: dxf[64 pix][20]
    if (jg == 0) {
        float* d0 = &xs[(p0 + 0) * 20];
        float* d1 = &xs[(p0 + 1) * 20];
        *(float4*)&d0[0]  = make_float4(dx0[0],  dx0[1],  dx0[2],  dx0[3]);
        *(float4*)&d0[4]  = make_float4(dx0[4],  dx0[5],  dx0[6],  dx0[7]);
        *(float4*)&d0[8]  = make_float4(dx0[8],  dx0[9],  dx0[10], dx0[11]);
        *(float4*)&d0[12] = make_float4(dx0[12], dx0[13], dx0[14], dx0[15]);
        *(float4*)&d1[0]  = make_float4(dx1[0],  dx1[1],  dx1[2],  dx1[3]);
        *(float4*)&d1[4]  = make_float4(dx1[4],  dx1[5],  dx1[6],  dx1[7]);
        *(float4*)&d1[8]  = make_float4(dx1[8],  dx1[9],  dx1[10], dx1[11]);
        *(float4*)&d1[12] = make_float4(dx1[12], dx1[13], dx1[14], dx1[15]);
    }
    __syncthreads();

    // epilogue: thread = (pixel pp=t>>2, c4=t&3)
    const int pp  = t >> 2;
    const int c4o = (t & 3) << 2;
    float4 ds  = *(const float4*)&xs[pp*20 + c4o];
    float4 xc2 = *(const float4*)&perc[pp*132 + c4o];
    const int ppy = pp >> 3, ppx = pp & 7;
    const int pix2 = (b << 16) + ((ty0 + ppy) << 8) + (tx0 + ppx);
    float fire = (stoch_s[pix2] > 0.5f) ? 1.f : 0.f;
    float4 xn;
    xn.x = fmaf(fire, ds.x, xc2.x);
    xn.y = fmaf(fire, ds.y, xc2.y);
    xn.z = fmaf(fire, ds.z, xc2.z);
    xn.w = fmaf(fire, ds.w, xc2.w);
    *(float4*)&xmid[(size_t)pix2*16 + c4o] = xn;
    if ((t & 3) == 0) alpha_out[pix2] = xn.w;   // channel 3
}

// In-place life masking: reads alpha_new from the separate plane (race-free).
__global__ void step_mask(float* __restrict__ xbuf,
                          const float* __restrict__ alpha,
                          const float* __restrict__ prelife,
                          const float* __restrict__ valid) {
    int pix = blockIdx.x * 256 + threadIdx.x;
    int b = pix >> 16;
    int y = (pix >> 8) & 255;
    int x = pix & 255;
    float m = -INFINITY;
    #pragma unroll
    for (int dy = -1; dy <= 1; dy++) {
        #pragma unroll
        for (int dxo = -1; dxo <= 1; dxo++) {
            int yy = y + dy, xx = x + dxo;
            if ((unsigned)yy < 256u && (unsigned)xx < 256u)
                m = fmaxf(m, alpha[(b << 16) + (yy << 8) + xx]);
        }
    }
    float life = (prelife[pix] != 0.f && m > 0.1f) ? 1.f : 0.f;
    float s = life * valid[pix];
    float4* xp = (float4*)&xbuf[(size_t)pix << 4];
    #pragma unroll
    for (int i = 0; i < 4; i++) {
        float4 v = xp[i];
        v.x *= s; v.y *= s; v.z *= s; v.w *= s;
        xp[i] = v;
    }
}

extern "C" void kernel_launch(void* const* d_in, const int* in_sizes, int n_in,
                              void* d_out, int out_size, void* d_ws, size_t ws_size,
                              hipStream_t stream) {
    const float* x0    = (const float*)d_in[0];
    const float* valid = (const float*)d_in[1];
    const float* stoch = (const float*)d_in[2];
    const float* W0    = (const float*)d_in[3];
    const float* b0    = (const float*)d_in[4];
    const float* W1    = (const float*)d_in[5];

    float* ws      = (float*)d_ws;
    float* xA      = ws;                 // 8388608 floats
    float* alpha   = ws + 8388608;       // 524288
    float* prelife = ws + 8912896;       // 524288
    float* filt    = ws + 9437184;       // 294 (+pad)
    float* out     = (float*)d_out;

    init_kernel<<<1, 64, 0, stream>>>(W0, filt);

    const float* src = x0;
    for (int k = 1; k <= 16; k++) {
        float* dst = (k & 1) ? xA : out;   // step 16 (even) lands in d_out
        step_main<<<dim3(32,32,8), 256, 0, stream>>>(
            src, dst, alpha, prelife, filt, W0, b0, W1,
            stoch + (size_t)(k-1)*NPIX);
        step_mask<<<NPIX/256, 256, 0, stream>>>(dst, alpha, prelife, valid);
        src = dst;
    }
}